// Round 6
// baseline (263.495 us; speedup 1.0000x reference)
//
#include <hip/hip_runtime.h>
#include <hip/hip_bf16.h>

// GCN 2-layer, N=100000, E=1.6M, 64->64(relu)->32.
// out[d] = dis[d]*(sum_{s in N(d)} dis[s]*h[s] + dis[d]*h[d]) + b  (per layer).
// Pipeline (6 dispatches):
//  pass1: partition edges into 782 coarse dst-ranges (128 dsts each) via LDS
//         histogram + chunk-reserved appends; records packed (src<<7)|(dst&127).
//         Fused with gemm1 (x@W1 -> h1T bf16 UNSCALED, SLICED layout [4][N][16]).
//  pass2: one block per range bins its 128 dsts via LDS cursors; publishes
//         cnt + dis[] = rsqrt(deg+1).
//  agg1_sliced: XCD feature-slicing. 4 slices x 16 feats; slice = bid&3 so the
//         blockIdx%8 round-robin XCD mapping pins slice s to XCDs {s, s+4}.
//         Working set 3.2 MB/slice fits the 4 MB per-XCD L2 -> gathers become
//         L2 hits instead of the ~2.4 TB/s L3 random path. 4 lanes/node,
//         32 B/edge gathers. z1T bf16 sliced.
//  gemm2: 32-row tile, reads sliced z1T, writes h2sT [2][N][16] bf16 * dis.
//  agg2_sliced: 2 slices x 16 feats of h2s (3.2 MB/slice), same scheme.

constexpr int N = 100000;
constexpr int E = 1600000;
constexpr int NBINS = 782;     // coarse ranges of 128 dsts
constexpr int CAP  = 2688;     // records per range (mean 2046, +14 sigma)
constexpr int P1B  = 391;      // pass1 blocks (4096 edges each)
constexpr int GB   = 1563;     // gemm1 blocks (64 rows each)
constexpr int NB64 = 1563;     // ceil(N/64) node-groups for agg kernels

// ---- fused: pass1 partition (bid<P1B) | gemm1 outer-product (else) ----
__global__ void __launch_bounds__(256) fused_pass1_gemm1(
    const float* __restrict__ x, const float* __restrict__ W1,
    __hip_bfloat16* __restrict__ h1T,
    const int* __restrict__ src, const int* __restrict__ dst,
    int* __restrict__ cursor, unsigned* __restrict__ rec) {
    __shared__ float ws[64][64];    // 16 KB (pass1 reuses as int scratch)
    __shared__ float xsT[64][64];   // 16 KB
    const int bid = blockIdx.x;
    const int t = threadIdx.x;
    if (bid < P1B) {
        int* hist  = (int*)ws;          // 784
        int* rbase = hist + 784;        // 784
        int* rcur  = rbase + 784;       // 784
        for (int i = t; i < 784; i += 256) hist[i] = 0;
        __syncthreads();
        int myd[16], mys[16];
        const int e0 = bid * 4096;
#pragma unroll
        for (int it = 0; it < 16; ++it) {
            int idx = e0 + it * 256 + t;
            bool ok = idx < E;
            myd[it] = ok ? dst[idx] : -1;
            mys[it] = ok ? src[idx] : 0;
            if (ok) atomicAdd(&hist[myd[it] >> 7], 1);
        }
        __syncthreads();
        for (int i = t; i < 784; i += 256) {
            int h = hist[i];
            rbase[i] = (h > 0) ? atomicAdd(&cursor[i], h) : 0;
            rcur[i] = 0;
        }
        __syncthreads();
#pragma unroll
        for (int it = 0; it < 16; ++it) {
            if (myd[it] >= 0) {
                int cb = myd[it] >> 7;
                int r = atomicAdd(&rcur[cb], 1);
                int pos = rbase[cb] + r;
                if (pos < CAP)
                    rec[(size_t)cb * CAP + pos] =
                        ((unsigned)mys[it] << 7) | ((unsigned)myd[it] & 127u);
            }
        }
    } else {
        // ---- gemm block: 64 rows, outer-product 4x4 per thread ----
        const int row0 = (bid - P1B) * 64;
        for (int i = t * 4; i < 64 * 64; i += 1024) {
            float4 v = *(const float4*)(W1 + i);
            ws[i >> 6][i & 63]       = v.x;
            ws[i >> 6][(i & 63) + 1] = v.y;
            ws[i >> 6][(i & 63) + 2] = v.z;
            ws[i >> 6][(i & 63) + 3] = v.w;
        }
        {
            const int r  = t & 63;
            const int k0 = (t >> 6) * 16;
            const int gr = row0 + r;
            if (gr < N) {
#pragma unroll
                for (int kk = 0; kk < 16; kk += 4) {
                    float4 v = *(const float4*)(x + (size_t)gr * 64 + k0 + kk);
                    xsT[k0 + kk][r]     = v.x;
                    xsT[k0 + kk + 1][r] = v.y;
                    xsT[k0 + kk + 2][r] = v.z;
                    xsT[k0 + kk + 3][r] = v.w;
                }
            } else {
#pragma unroll
                for (int kk = 0; kk < 16; ++kk) xsT[k0 + kk][r] = 0.0f;
            }
        }
        __syncthreads();
        const int c4 = (t & 15) * 4;
        const int r4 = (t >> 4) * 4;
        float acc[4][4];
#pragma unroll
        for (int i = 0; i < 4; ++i)
#pragma unroll
            for (int j = 0; j < 4; ++j) acc[i][j] = 0.0f;
#pragma unroll 4
        for (int k = 0; k < 64; ++k) {
            float4 wv = *(const float4*)&ws[k][c4];
            float4 xv = *(const float4*)&xsT[k][r4];
            float xa[4] = {xv.x, xv.y, xv.z, xv.w};
            float wa[4] = {wv.x, wv.y, wv.z, wv.w};
#pragma unroll
            for (int i = 0; i < 4; ++i)
#pragma unroll
                for (int j = 0; j < 4; ++j) acc[i][j] += xa[i] * wa[j];
        }
        // write to SLICED layout: h1T[c4>>4][row][c4&15 .. +4]
        const int slice = c4 >> 4;
        const int off   = c4 & 15;
#pragma unroll
        for (int i = 0; i < 4; ++i) {
            const int gr = row0 + r4 + i;
            if (gr < N) {
                unsigned short o[4];
#pragma unroll
                for (int j = 0; j < 4; ++j)
                    o[j] = __bfloat16_as_ushort(__float2bfloat16(acc[i][j]));
                *(ushort4*)((unsigned short*)h1T +
                            ((size_t)slice * N + gr) * 16 + off) =
                    *(const ushort4*)o;
            }
        }
    }
}

// ---- pass2: bin one 128-dst range; single-writer buckets, no global atomics.
// Publishes cnt + dis[] = rsqrt(deg+1). ----
__global__ void __launch_bounds__(256) pass2_kernel(
    const unsigned* __restrict__ rec, const int* __restrict__ cursor,
    unsigned* __restrict__ pedge, int* __restrict__ cnt,
    float* __restrict__ dis) {
    __shared__ int cur[128];
    const int cb = blockIdx.x;
    const int t = threadIdx.x;
    if (t < 128) cur[t] = 0;
    __syncthreads();
    int m = cursor[cb];
    if (m > CAP) m = CAP;
    const int row0 = cb * 128;
    for (int i = t; i < m; i += 256) {
        unsigned u = rec[(size_t)cb * CAP + i];
        int dl = (int)(u & 127u);
        unsigned s = u >> 7;
        int r = atomicAdd(&cur[dl], 1);
        if (r < 64) pedge[((size_t)(row0 + dl) << 6) + r] = s;
    }
    __syncthreads();
    if (t < 128 && row0 + t < N) {
        const int c = cur[t];
        cnt[row0 + t] = c;
        dis[row0 + t] = rsqrtf((float)c + 1.0f);
    }
}

__device__ __forceinline__ void bf4_fma(float* acc, uint2 r, float w) {
    acc[0] += __uint_as_float(r.x << 16) * w;
    acc[1] += __uint_as_float(r.x & 0xffff0000u) * w;
    acc[2] += __uint_as_float(r.y << 16) * w;
    acc[3] += __uint_as_float(r.y & 0xffff0000u) * w;
}

__device__ __forceinline__ void bf4_acc(float* acc, uint2 r) {
    acc[0] += __uint_as_float(r.x << 16);
    acc[1] += __uint_as_float(r.x & 0xffff0000u);
    acc[2] += __uint_as_float(r.y << 16);
    acc[3] += __uint_as_float(r.y & 0xffff0000u);
}

// ---- layer-1 agg, XCD-sliced: slice = bid&3 (16 feats, 3.2 MB working set
// fits per-XCD L2). 4 lanes/node x 4 feats; 64 nodes/block-group.
// z1T[slice][n][16] = relu(dis[n]*(sum dis[s]*h1[s] + dis[n]*h1[n]) + b). ----
__global__ void __launch_bounds__(256) agg1_sliced_kernel(
    const __hip_bfloat16* __restrict__ h1T, const unsigned* __restrict__ pedge,
    const int* __restrict__ cnt, const float* __restrict__ dis,
    const float* __restrict__ b, __hip_bfloat16* __restrict__ z1T) {
    const int bid = blockIdx.x;
    const int slice = bid & 3;
    const int t = threadIdx.x;
    const int nid = (bid >> 2) * 64 + (t >> 2);
    if (nid >= N) return;
    const int f4 = (t & 3) * 4;
    const unsigned short* hp =
        (const unsigned short*)h1T + (size_t)slice * N * 16;
    const int c = cnt[nid];
    const int deg = (c < 64) ? c : 64;
    const size_t base = (size_t)nid << 6;
    float acc[4] = {0.f, 0.f, 0.f, 0.f};
    int j = 0;
    for (; j + 2 <= deg; j += 2) {
        uint2 ss = *(const uint2*)(pedge + base + j);
        float w0 = dis[ss.x], w1 = dis[ss.y];
        uint2 r0 = *(const uint2*)(hp + (size_t)ss.x * 16 + f4);
        uint2 r1 = *(const uint2*)(hp + (size_t)ss.y * 16 + f4);
        bf4_fma(acc, r0, w0);
        bf4_fma(acc, r1, w1);
    }
    if (j < deg) {
        unsigned s0 = pedge[base + j];
        float w0 = dis[s0];
        uint2 r0 = *(const uint2*)(hp + (size_t)s0 * 16 + f4);
        bf4_fma(acc, r0, w0);
    }
    const float dn = dis[nid];
    uint2 sr = *(const uint2*)(hp + (size_t)nid * 16 + f4);
    bf4_fma(acc, sr, dn);  // self term
    float4 bv = *(const float4*)(b + slice * 16 + f4);
    float bb[4] = {bv.x, bv.y, bv.z, bv.w};
    unsigned short o[4];
#pragma unroll
    for (int i = 0; i < 4; ++i) {
        float v = fmaxf(dn * acc[i] + bb[i], 0.0f);
        o[i] = __bfloat16_as_ushort(__float2bfloat16(v));
    }
    *(ushort4*)((unsigned short*)z1T + ((size_t)slice * N + nid) * 16 + f4) =
        *(const ushort4*)o;
}

// ---- gemm2: h2sT[n] = (z1 @ W2)[n] * dis[n] -> bf16 sliced [2][N][16] ----
__global__ void __launch_bounds__(256) gemm2_kernel(
    const __hip_bfloat16* __restrict__ z1T, const float* __restrict__ W2,
    const float* __restrict__ dis, __hip_bfloat16* __restrict__ h2sT) {
    __shared__ float ws[64][32];
    __shared__ float xs[32][64];
    const int t = threadIdx.x;
    for (int i = t; i < 64 * 32; i += 256) ws[i >> 5][i & 31] = W2[i];
    const int row0 = blockIdx.x * 32;
    const unsigned short* Zp = (const unsigned short*)z1T;
    {
        // 256 threads: 32 rows x 8 chunks of 8 feats (16 B) from sliced z1T
        const int r  = t >> 3;
        const int ch = t & 7;
        const int sl = ch >> 1;
        const int hf = (ch & 1) * 8;
        uint4 v = *(const uint4*)(Zp + ((size_t)sl * N + row0 + r) * 16 + hf);
        float* xd = &xs[r][sl * 16 + hf];
        const unsigned u[4] = {v.x, v.y, v.z, v.w};
#pragma unroll
        for (int k = 0; k < 4; ++k) {
            xd[2 * k]     = __uint_as_float(u[k] << 16);
            xd[2 * k + 1] = __uint_as_float(u[k] & 0xffff0000u);
        }
    }
    __syncthreads();
    const int cc = t & 31;
    const int rb = (t >> 5) * 4;
    float oacc[4] = {0.f, 0.f, 0.f, 0.f};
    for (int k0 = 0; k0 < 64; k0 += 4) {
        float w0 = ws[k0][cc], w1 = ws[k0 + 1][cc];
        float w2 = ws[k0 + 2][cc], w3 = ws[k0 + 3][cc];
#pragma unroll
        for (int i = 0; i < 4; ++i) {
            float4 xv = *(const float4*)&xs[rb + i][k0];
            oacc[i] += xv.x * w0;
            oacc[i] += xv.y * w1;
            oacc[i] += xv.z * w2;
            oacc[i] += xv.w * w3;
        }
    }
    const int sl  = cc >> 4;
    const int off = cc & 15;
#pragma unroll
    for (int i = 0; i < 4; ++i) {
        const int row = row0 + rb + i;
        ((unsigned short*)h2sT)[((size_t)sl * N + row) * 16 + off] =
            __bfloat16_as_ushort(__float2bfloat16(oacc[i] * dis[row]));
    }
}

// ---- layer-2 agg, XCD-sliced: slice = bid&1 (16 feats, 3.2 MB), 4 lanes/node.
// h2sT already carries one dis factor; pure accumulation. ----
__global__ void __launch_bounds__(256) agg2_sliced_kernel(
    const __hip_bfloat16* __restrict__ h2sT, const unsigned* __restrict__ pedge,
    const int* __restrict__ cnt, const float* __restrict__ dis,
    const float* __restrict__ b, float* __restrict__ out) {
    const int bid = blockIdx.x;
    const int slice = bid & 1;
    const int t = threadIdx.x;
    const int nid = (bid >> 1) * 64 + (t >> 2);
    if (nid >= N) return;
    const int f4 = (t & 3) * 4;
    const unsigned short* hp =
        (const unsigned short*)h2sT + (size_t)slice * N * 16;
    const int c = cnt[nid];
    const int deg = (c < 64) ? c : 64;
    const size_t base = (size_t)nid << 6;
    float acc[4] = {0.f, 0.f, 0.f, 0.f};
    int j = 0;
    for (; j + 2 <= deg; j += 2) {
        uint2 ss = *(const uint2*)(pedge + base + j);
        uint2 r0 = *(const uint2*)(hp + (size_t)ss.x * 16 + f4);
        uint2 r1 = *(const uint2*)(hp + (size_t)ss.y * 16 + f4);
        bf4_acc(acc, r0);
        bf4_acc(acc, r1);
    }
    if (j < deg) {
        unsigned s0 = pedge[base + j];
        uint2 r0 = *(const uint2*)(hp + (size_t)s0 * 16 + f4);
        bf4_acc(acc, r0);
    }
    uint2 sr = *(const uint2*)(hp + (size_t)nid * 16 + f4);
    bf4_acc(acc, sr);  // self term (h2s already has one dis factor)
    const float dn = dis[nid];
    float4 bv = *(const float4*)(b + slice * 16 + f4);
    *(float4*)(out + (size_t)nid * 32 + slice * 16 + f4) =
        make_float4(dn * acc[0] + bv.x, dn * acc[1] + bv.y,
                    dn * acc[2] + bv.z, dn * acc[3] + bv.w);
}

extern "C" void kernel_launch(void* const* d_in, const int* in_sizes, int n_in,
                              void* d_out, int out_size, void* d_ws, size_t ws_size,
                              hipStream_t stream) {
    const float* x  = (const float*)d_in[0];
    const int*   ei = (const int*)d_in[1];
    const float* W1 = (const float*)d_in[2];
    const float* b1 = (const float*)d_in[3];
    const float* W2 = (const float*)d_in[4];
    const float* b2 = (const float*)d_in[5];
    float* out = (float*)d_out;

    const int* src = ei;
    const int* dst = ei + E;

    constexpr size_t NP = 100352;
    int*      cursor = (int*)d_ws;                             // 1024 ints
    int*      cnt    = cursor + 1024;                          // NP ints
    float*    dis    = (float*)(cnt + NP);                     // NP floats
    unsigned* pedge  = (unsigned*)(dis + NP);                  // N*64 (25.6 MB)
    unsigned* rec    = pedge + (size_t)N * 64;                 // NBINS*CAP u32 (8.4 MB)
    __hip_bfloat16* h1T  = (__hip_bfloat16*)(rec + (size_t)NBINS * CAP); // [4][N][16]
    __hip_bfloat16* z1T  = h1T + (size_t)N * 64;                          // [4][N][16]
    __hip_bfloat16* h2sT = z1T + (size_t)N * 64;                          // [2][N][16]

    hipMemsetAsync(cursor, 0, 1024 * sizeof(int), stream);
    fused_pass1_gemm1<<<P1B + GB, 256, 0, stream>>>(x, W1, h1T, src, dst,
                                                    cursor, rec);
    pass2_kernel<<<NBINS, 256, 0, stream>>>(rec, cursor, pedge, cnt, dis);
    agg1_sliced_kernel<<<4 * NB64, 256, 0, stream>>>(h1T, pedge, cnt, dis, b1,
                                                     z1T);
    gemm2_kernel<<<N / 32, 256, 0, stream>>>(z1T, W2, dis, h2sT);
    agg2_sliced_kernel<<<2 * NB64, 256, 0, stream>>>(h2sT, pedge, cnt, dis, b2,
                                                     out);
}